// Round 7
// baseline (92.657 us; speedup 1.0000x reference)
//
#include <hip/hip_runtime.h>
#include <cfloat>

typedef float f32x16 __attribute__((ext_vector_type(16)));
typedef short s16x8  __attribute__((ext_vector_type(8)));

// Problem constants
constexpr int B = 4, N = 8192;
constexpr int IB   = 4;              // 32-row i-blocks per wave
constexpr int JT   = 8;              // 32-col j-tiles per wave
constexpr int ISTR = N / (32 * IB);  // 64 i-strips per batch
constexpr int JSTR = N / (32 * JT);  // 32 j-strips per batch
constexpr int NSEG = 2 * B;          // 8 (dir,b) segments

__device__ __forceinline__ unsigned short f2bf(float x) {   // RNE bf16
    unsigned int u = __float_as_uint(x);
    u += 0x7fffu + ((u >> 16) & 1u);
    return (unsigned short)(u >> 16);
}
__device__ __forceinline__ float bf2f(unsigned short h) {
    return __uint_as_float((unsigned int)h << 16);
}

// Pack A (pred) / B (gt) MFMA fragments, K=16 slot plan (per point):
//   A row : [-2xh,-2yh,-2zh, -2xl,-2yl,-2zl, -2xh,-2yh | -2zh, 1, 1, pnh, pnl, 0,0,0]
//   B col : [ xh,  yh,  zh,   xh,  yh,  zh,   xl,  yl  |  zl, gnh, gnl, 1, 1, 0,0,0]
// => MFMA output c = pn + gn - 2*p.g  (full squared distance, err ~1e-3)
// Fragment layout (32x32x16): lane holds (row|col)=lane&31, k = 8*(lane>>5)+kk.
__global__ __launch_bounds__(256) void pack_kernel(
        const float* __restrict__ pred, const float* __restrict__ gt,
        uint4* __restrict__ Apack, uint4* __restrict__ Bpack) {
    int id   = blockIdx.x * 256 + threadIdx.x;   // [0, 131072)
    int side = id >> 16;                         // 0 = pred->A, 1 = gt->B
    int rem  = id & 65535;
    int b    = rem >> 14;
    int t2   = rem & 16383;
    int blk  = t2 >> 6;                          // 32-point block [0,256)
    int lane = t2 & 63;
    int h    = lane >> 5;
    int row  = blk * 32 + (lane & 31);

    const float* s = (side ? gt : pred) + ((size_t)b * N + row) * 3;
    float x = s[0], y = s[1], z = s[2];
    unsigned short xh = f2bf(x), yh = f2bf(y), zh = f2bf(z);
    float xl = x - bf2f(xh), yl = y - bf2f(yh), zl = z - bf2f(zh);
    float n = fmaf(x, x, fmaf(y, y, z * z));
    unsigned short nh = f2bf(n);
    unsigned short nl = f2bf(n - bf2f(nh));
    const unsigned short ONE = 0x3F80;

    unsigned short w[8];
    if (side == 0) {   // A side: -2 folded in (exact for hi parts)
        unsigned short mxh = f2bf(-2.f * bf2f(xh));
        unsigned short myh = f2bf(-2.f * bf2f(yh));
        unsigned short mzh = f2bf(-2.f * bf2f(zh));
        if (h == 0) {
            w[0] = mxh; w[1] = myh; w[2] = mzh;
            w[3] = f2bf(-2.f * xl); w[4] = f2bf(-2.f * yl); w[5] = f2bf(-2.f * zl);
            w[6] = mxh; w[7] = myh;
        } else {
            w[0] = mzh; w[1] = ONE; w[2] = ONE; w[3] = nh; w[4] = nl;
            w[5] = 0; w[6] = 0; w[7] = 0;
        }
    } else {           // B side
        if (h == 0) {
            w[0] = xh; w[1] = yh; w[2] = zh;
            w[3] = xh; w[4] = yh; w[5] = zh;
            w[6] = f2bf(xl); w[7] = f2bf(yl);
        } else {
            w[0] = f2bf(zl); w[1] = nh; w[2] = nl; w[3] = ONE; w[4] = ONE;
            w[5] = 0; w[6] = 0; w[7] = 0;
        }
    }
    uint4 out;
    out.x = (unsigned)w[0] | ((unsigned)w[1] << 16);
    out.y = (unsigned)w[2] | ((unsigned)w[3] << 16);
    out.z = (unsigned)w[4] | ((unsigned)w[5] << 16);
    out.w = (unsigned)w[6] | ((unsigned)w[7] << 16);
    (side ? Bpack : Apack)[((size_t)b * 256 + blk) * 64 + lane] = out;
}

// One wave per block. Wave computes a 128x256 tile of the distance matrix via
// 32 MFMAs; accumulates row-mins in regs (full j-strip) and col-mins per
// j-tile (full i-strip-of-wave). Partial mins stored bf16 to slabs.
__global__ __launch_bounds__(64, 3) void chamfer_mfma(
        const uint4* __restrict__ Apack, const uint4* __restrict__ Bpack,
        unsigned short* __restrict__ rowpart, unsigned short* __restrict__ colpart) {
    int bid = blockIdx.x;
    int b   = bid / (ISTR * JSTR);
    int r0  = bid % (ISTR * JSTR);
    int is  = r0 / JSTR;
    int js  = r0 % JSTR;
    int lane = threadIdx.x;

    s16x8 afr[IB];
#pragma unroll
    for (int ib = 0; ib < IB; ++ib)
        afr[ib] = __builtin_bit_cast(s16x8,
            Apack[((size_t)b * 256 + is * IB + ib) * 64 + lane]);

    float rowm[IB][16];
#pragma unroll
    for (int ib = 0; ib < IB; ++ib)
#pragma unroll
        for (int r = 0; r < 16; ++r) rowm[ib][r] = FLT_MAX;

    __shared__ float lds[64][20];   // pad 20: b128-alignable rows, low conflicts

#pragma unroll 1
    for (int jt = 0; jt < JT; ++jt) {
        int jb = js * JT + jt;
        s16x8 bfr = __builtin_bit_cast(s16x8,
            Bpack[((size_t)b * 256 + jb) * 64 + lane]);
        float colacc = FLT_MAX;
#pragma unroll
        for (int ib = 0; ib < IB; ++ib) {
            f32x16 zc = {};
            f32x16 c = __builtin_amdgcn_mfma_f32_32x32x16_bf16(afr[ib], bfr, zc, 0, 0, 0);
            // row-min accumulate (row = (r&3)+8*(r>>2)+4*(lane>>5), col = lane&31)
#pragma unroll
            for (int r = 0; r < 16; ++r) rowm[ib][r] = fminf(rowm[ib][r], c[r]);
            // col-min tree over this lane's 16 rows (min3 fusion)
            float u0 = fminf(fminf(c[0], c[1]), c[2]);
            float u1 = fminf(fminf(c[3], c[4]), c[5]);
            float u2 = fminf(fminf(c[6], c[7]), c[8]);
            float u3 = fminf(fminf(c[9], c[10]), c[11]);
            float u4 = fminf(fminf(c[12], c[13]), c[14]);
            float m  = fminf(fminf(fminf(u0, u1), fminf(u2, u3)), fminf(u4, c[15]));
            colacc = fminf(colacc, m);
        }
        // combine halves (lane ^ 32 has the other 16 rows of this col)
        float colmin = fminf(colacc, __shfl_xor(colacc, 32));
        if (lane < 32)
            colpart[((size_t)b * ISTR + is) * N + jb * 32 + lane] = f2bf(colmin);
    }

    // Row-min cross-lane reduction via LDS transpose, one i-block at a time.
#pragma unroll 1
    for (int ib = 0; ib < IB; ++ib) {
#pragma unroll
        for (int r = 0; r < 16; ++r) lds[lane][r] = rowm[ib][r];
        __syncthreads();
        int rr = lane & 31;                       // row within i-block
        int h  = (rr >> 2) & 1;                   // which lane-half holds it
        int rg = (rr & 3) | ((rr >> 3) << 2);     // reg index
        float m = FLT_MAX;
#pragma unroll
        for (int cc = 0; cc < 16; ++cc) {
            int srcl = h * 32 + (lane >> 5) * 16 + cc;
            m = fminf(m, lds[srcl][rg]);
        }
        m = fminf(m, __shfl_xor(m, 32));          // other 16 cols
        if (lane < 32)
            rowpart[((size_t)b * JSTR + js) * N + is * (32 * IB) + ib * 32 + rr] = f2bf(m);
        __syncthreads();
    }
}

// 256 blocks: segs 0-3 reduce rowpart (min over 32 j-strips), segs 4-7 reduce
// colpart (min over 64 i-strips); emit per-block sum & max partials.
__global__ __launch_bounds__(256) void reduce1(
        const unsigned short* __restrict__ rowpart,
        const unsigned short* __restrict__ colpart,
        float* __restrict__ bsum, float* __restrict__ bmax) {
    int bk  = blockIdx.x;
    int seg = bk >> 5;                 // 0..7
    int idx = (bk & 31) * 256 + threadIdx.x;
    const unsigned short* base;
    int strips;
    if (seg < 4) { base = rowpart + (size_t)seg * JSTR * N + idx; strips = JSTR; }
    else         { base = colpart + (size_t)(seg - 4) * ISTR * N + idx; strips = ISTR; }
    float v = FLT_MAX;
    for (int s = 0; s < strips; ++s)
        v = fminf(v, bf2f(base[(size_t)s * N]));
    __shared__ float ssum[256], smax[256];
    ssum[threadIdx.x] = v;
    smax[threadIdx.x] = v;
    __syncthreads();
    for (int st = 128; st > 0; st >>= 1) {
        if (threadIdx.x < st) {
            ssum[threadIdx.x] += ssum[threadIdx.x + st];
            smax[threadIdx.x] = fmaxf(smax[threadIdx.x], smax[threadIdx.x + st]);
        }
        __syncthreads();
    }
    if (threadIdx.x == 0) { bsum[bk] = ssum[0]; bmax[bk] = smax[0]; }
}

// Combine 256 block partials. Blocks [seg*32, seg*32+32) belong to segment seg.
__global__ __launch_bounds__(256) void final_combine(
        const float* __restrict__ bsum, const float* __restrict__ bmax,
        float* __restrict__ out) {
    int t = threadIdx.x;
    __shared__ float ss[256], sm[256];
    ss[t] = bsum[t];
    sm[t] = bmax[t];
    __syncthreads();
    for (int st = 128; st > 0; st >>= 1) {
        if (t < st) ss[t] += ss[t + st];
        __syncthreads();
    }
    for (int st = 16; st > 0; st >>= 1) {
        if ((t & 31) < st) sm[t] = fmaxf(sm[t], sm[t + st]);
        __syncthreads();
    }
    if (t == 0) {
        float hsum = 0.f;
#pragma unroll
        for (int k = 0; k < NSEG; ++k) hsum += sm[k * 32];
        out[0] = ss[0] / (float)(B * N);   // chamfer
        out[1] = hsum / (float)B;          // hausdorff
    }
}

extern "C" void kernel_launch(void* const* d_in, const int* in_sizes, int n_in,
                              void* d_out, int out_size, void* d_ws, size_t ws_size,
                              hipStream_t stream) {
    const float* pred = (const float*)d_in[0];
    const float* gt   = (const float*)d_in[1];
    float* out = (float*)d_out;

    char* p = (char*)d_ws;
    uint4* Apack = (uint4*)p;                 p += (size_t)B * 256 * 64 * 16;  // 1 MB
    uint4* Bpack = (uint4*)p;                 p += (size_t)B * 256 * 64 * 16;  // 1 MB
    unsigned short* colpart = (unsigned short*)p; p += (size_t)B * ISTR * N * 2; // 4 MB
    unsigned short* rowpart = (unsigned short*)p; p += (size_t)B * JSTR * N * 2; // 2 MB
    float* bsum = (float*)p;                  p += 256 * 4;
    float* bmax = (float*)p;

    pack_kernel<<<512, 256, 0, stream>>>(pred, gt, Apack, Bpack);
    chamfer_mfma<<<B * ISTR * JSTR, 64, 0, stream>>>(Apack, Bpack, rowpart, colpart);
    reduce1<<<256, 256, 0, stream>>>(rowpart, colpart, bsum, bmax);
    final_combine<<<1, 256, 0, stream>>>(bsum, bmax, out);
}

// Round 8
// 53.851 us; speedup vs baseline: 1.7206x; 1.7206x over previous
//
#include <hip/hip_runtime.h>
#include <cfloat>

typedef float f32x16 __attribute__((ext_vector_type(16)));
typedef short s16x8  __attribute__((ext_vector_type(8)));

// Problem constants
constexpr int B = 4, N = 8192;
constexpr int IB   = 4;              // 32-row i-blocks per wave
constexpr int JT   = 8;              // 32-col j-tiles per wave
constexpr int ISTR = N / (32 * IB);  // 64 i-strips per batch
constexpr int JSTR = N / (32 * JT);  // 32 j-strips per batch
constexpr int NSEG = 2 * B;          // 8 (dir,b) segments

__device__ __forceinline__ unsigned short f2bf(float x) {   // RNE bf16
    unsigned int u = __float_as_uint(x);
    u += 0x7fffu + ((u >> 16) & 1u);
    return (unsigned short)(u >> 16);
}
__device__ __forceinline__ float bf2f(unsigned short h) {
    return __uint_as_float((unsigned int)h << 16);
}

// Pack A (pred) / B (gt) MFMA fragments, K=16 slot plan (per point):
//   A row : [-2xh,-2yh,-2zh, -2xl,-2yl,-2zl, -2xh,-2yh | -2zh, 1, 1, pnh, pnl, 0,0,0]
//   B col : [ xh,  yh,  zh,   xh,  yh,  zh,   xl,  yl  |  zl, gnh, gnl, 1, 1, 0,0,0]
// => MFMA output c = pn + gn - 2*p.g  (full squared distance, err ~1e-3)
// Fragment layout (32x32x16): lane holds (row|col)=lane&31, k = 8*(lane>>5)+kk.
__global__ __launch_bounds__(256) void pack_kernel(
        const float* __restrict__ pred, const float* __restrict__ gt,
        uint4* __restrict__ Apack, uint4* __restrict__ Bpack) {
    int id   = blockIdx.x * 256 + threadIdx.x;   // [0, 131072)
    int side = id >> 16;                         // 0 = pred->A, 1 = gt->B
    int rem  = id & 65535;
    int b    = rem >> 14;
    int t2   = rem & 16383;
    int blk  = t2 >> 6;                          // 32-point block [0,256)
    int lane = t2 & 63;
    int h    = lane >> 5;
    int row  = blk * 32 + (lane & 31);

    const float* s = (side ? gt : pred) + ((size_t)b * N + row) * 3;
    float x = s[0], y = s[1], z = s[2];
    unsigned short xh = f2bf(x), yh = f2bf(y), zh = f2bf(z);
    float xl = x - bf2f(xh), yl = y - bf2f(yh), zl = z - bf2f(zh);
    float n = fmaf(x, x, fmaf(y, y, z * z));
    unsigned short nh = f2bf(n);
    unsigned short nl = f2bf(n - bf2f(nh));
    const unsigned short ONE = 0x3F80;

    unsigned short w[8];
    if (side == 0) {   // A side: -2 folded in (exact for hi parts)
        unsigned short mxh = f2bf(-2.f * bf2f(xh));
        unsigned short myh = f2bf(-2.f * bf2f(yh));
        unsigned short mzh = f2bf(-2.f * bf2f(zh));
        if (h == 0) {
            w[0] = mxh; w[1] = myh; w[2] = mzh;
            w[3] = f2bf(-2.f * xl); w[4] = f2bf(-2.f * yl); w[5] = f2bf(-2.f * zl);
            w[6] = mxh; w[7] = myh;
        } else {
            w[0] = mzh; w[1] = ONE; w[2] = ONE; w[3] = nh; w[4] = nl;
            w[5] = 0; w[6] = 0; w[7] = 0;
        }
    } else {           // B side
        if (h == 0) {
            w[0] = xh; w[1] = yh; w[2] = zh;
            w[3] = xh; w[4] = yh; w[5] = zh;
            w[6] = f2bf(xl); w[7] = f2bf(yl);
        } else {
            w[0] = f2bf(zl); w[1] = nh; w[2] = nl; w[3] = ONE; w[4] = ONE;
            w[5] = 0; w[6] = 0; w[7] = 0;
        }
    }
    uint4 out;
    out.x = (unsigned)w[0] | ((unsigned)w[1] << 16);
    out.y = (unsigned)w[2] | ((unsigned)w[3] << 16);
    out.z = (unsigned)w[4] | ((unsigned)w[5] << 16);
    out.w = (unsigned)w[6] | ((unsigned)w[7] << 16);
    (side ? Bpack : Apack)[((size_t)b * 256 + blk) * 64 + lane] = out;
}

// One wave per block. Wave computes a 128x256 tile of the distance matrix via
// 32 MFMAs; accumulates row-mins in regs (full j-strip) and col-mins per
// j-tile (full i-strip-of-wave). Partial mins stored bf16 to slabs.
// NOTE: every access to rowm[][] uses compile-time indices (all loops fully
// unrolled) — runtime indexing would spill the array to scratch (rule #20;
// R7 had 245 MB of HBM scratch traffic from exactly this).
__global__ __launch_bounds__(64, 3) void chamfer_mfma(
        const uint4* __restrict__ Apack, const uint4* __restrict__ Bpack,
        unsigned short* __restrict__ rowpart, unsigned short* __restrict__ colpart) {
    int bid = blockIdx.x;
    int b   = bid / (ISTR * JSTR);
    int r0  = bid % (ISTR * JSTR);
    int is  = r0 / JSTR;
    int js  = r0 % JSTR;
    int lane = threadIdx.x;

    s16x8 afr[IB];
#pragma unroll
    for (int ib = 0; ib < IB; ++ib)
        afr[ib] = __builtin_bit_cast(s16x8,
            Apack[((size_t)b * 256 + is * IB + ib) * 64 + lane]);

    float rowm[IB][16];
#pragma unroll
    for (int ib = 0; ib < IB; ++ib)
#pragma unroll
        for (int r = 0; r < 16; ++r) rowm[ib][r] = FLT_MAX;

    // stride 17: gcd(17,32)=1 -> write conflicts 2-way (free), reads ~2-way.
    __shared__ float lds[64][17];

#pragma unroll 1
    for (int jt = 0; jt < JT; ++jt) {
        int jb = js * JT + jt;
        s16x8 bfr = __builtin_bit_cast(s16x8,
            Bpack[((size_t)b * 256 + jb) * 64 + lane]);
        float colacc = FLT_MAX;
#pragma unroll
        for (int ib = 0; ib < IB; ++ib) {
            f32x16 zc = {};
            f32x16 c = __builtin_amdgcn_mfma_f32_32x32x16_bf16(afr[ib], bfr, zc, 0, 0, 0);
            // row-min accumulate (row = (r&3)+8*(r>>2)+4*(lane>>5), col = lane&31)
#pragma unroll
            for (int r = 0; r < 16; ++r) rowm[ib][r] = fminf(rowm[ib][r], c[r]);
            // col-min tree over this lane's 16 rows (min3 fusion)
            float u0 = fminf(fminf(c[0], c[1]), c[2]);
            float u1 = fminf(fminf(c[3], c[4]), c[5]);
            float u2 = fminf(fminf(c[6], c[7]), c[8]);
            float u3 = fminf(fminf(c[9], c[10]), c[11]);
            float u4 = fminf(fminf(c[12], c[13]), c[14]);
            float m  = fminf(fminf(fminf(u0, u1), fminf(u2, u3)), fminf(u4, c[15]));
            colacc = fminf(colacc, m);
        }
        // combine halves (lane ^ 32 has the other 16 rows of this col)
        float colmin = fminf(colacc, __shfl_xor(colacc, 32));
        if (lane < 32)
            colpart[((size_t)b * ISTR + is) * N + jb * 32 + lane] = f2bf(colmin);
    }

    // Row-min cross-lane reduction via LDS transpose, FULLY UNROLLED so rowm
    // keeps compile-time indices (registers, not scratch).
#pragma unroll
    for (int ib = 0; ib < IB; ++ib) {
#pragma unroll
        for (int r = 0; r < 16; ++r) lds[lane][r] = rowm[ib][r];
        __syncthreads();
        int rr = lane & 31;                       // row within i-block
        int h  = (rr >> 2) & 1;                   // which lane-half holds it
        int rg = (rr & 3) | ((rr >> 3) << 2);     // reg index
        float m = FLT_MAX;
#pragma unroll
        for (int cc = 0; cc < 16; ++cc) {
            int srcl = h * 32 + (lane >> 5) * 16 + cc;
            m = fminf(m, lds[srcl][rg]);
        }
        m = fminf(m, __shfl_xor(m, 32));          // other 16 cols
        if (lane < 32)
            rowpart[((size_t)b * JSTR + js) * N + is * (32 * IB) + ib * 32 + rr] = f2bf(m);
        __syncthreads();
    }
}

// 256 blocks: segs 0-3 reduce rowpart (min over 32 j-strips), segs 4-7 reduce
// colpart (min over 64 i-strips); emit per-block sum & max partials.
__global__ __launch_bounds__(256) void reduce1(
        const unsigned short* __restrict__ rowpart,
        const unsigned short* __restrict__ colpart,
        float* __restrict__ bsum, float* __restrict__ bmax) {
    int bk  = blockIdx.x;
    int seg = bk >> 5;                 // 0..7
    int idx = (bk & 31) * 256 + threadIdx.x;
    const unsigned short* base;
    int strips;
    if (seg < 4) { base = rowpart + (size_t)seg * JSTR * N + idx; strips = JSTR; }
    else         { base = colpart + (size_t)(seg - 4) * ISTR * N + idx; strips = ISTR; }
    float v = FLT_MAX;
    for (int s = 0; s < strips; ++s)
        v = fminf(v, bf2f(base[(size_t)s * N]));
    __shared__ float ssum[256], smax[256];
    ssum[threadIdx.x] = v;
    smax[threadIdx.x] = v;
    __syncthreads();
    for (int st = 128; st > 0; st >>= 1) {
        if (threadIdx.x < st) {
            ssum[threadIdx.x] += ssum[threadIdx.x + st];
            smax[threadIdx.x] = fmaxf(smax[threadIdx.x], smax[threadIdx.x + st]);
        }
        __syncthreads();
    }
    if (threadIdx.x == 0) { bsum[bk] = ssum[0]; bmax[bk] = smax[0]; }
}

// Combine 256 block partials. Blocks [seg*32, seg*32+32) belong to segment seg.
__global__ __launch_bounds__(256) void final_combine(
        const float* __restrict__ bsum, const float* __restrict__ bmax,
        float* __restrict__ out) {
    int t = threadIdx.x;
    __shared__ float ss[256], sm[256];
    ss[t] = bsum[t];
    sm[t] = bmax[t];
    __syncthreads();
    for (int st = 128; st > 0; st >>= 1) {
        if (t < st) ss[t] += ss[t + st];
        __syncthreads();
    }
    for (int st = 16; st > 0; st >>= 1) {
        if ((t & 31) < st) sm[t] = fmaxf(sm[t], sm[t + st]);
        __syncthreads();
    }
    if (t == 0) {
        float hsum = 0.f;
#pragma unroll
        for (int k = 0; k < NSEG; ++k) hsum += sm[k * 32];
        out[0] = ss[0] / (float)(B * N);   // chamfer
        out[1] = hsum / (float)B;          // hausdorff
    }
}

extern "C" void kernel_launch(void* const* d_in, const int* in_sizes, int n_in,
                              void* d_out, int out_size, void* d_ws, size_t ws_size,
                              hipStream_t stream) {
    const float* pred = (const float*)d_in[0];
    const float* gt   = (const float*)d_in[1];
    float* out = (float*)d_out;

    char* p = (char*)d_ws;
    uint4* Apack = (uint4*)p;                 p += (size_t)B * 256 * 64 * 16;  // 1 MB
    uint4* Bpack = (uint4*)p;                 p += (size_t)B * 256 * 64 * 16;  // 1 MB
    unsigned short* colpart = (unsigned short*)p; p += (size_t)B * ISTR * N * 2; // 4 MB
    unsigned short* rowpart = (unsigned short*)p; p += (size_t)B * JSTR * N * 2; // 2 MB
    float* bsum = (float*)p;                  p += 256 * 4;
    float* bmax = (float*)p;

    pack_kernel<<<512, 256, 0, stream>>>(pred, gt, Apack, Bpack);
    chamfer_mfma<<<B * ISTR * JSTR, 64, 0, stream>>>(Apack, Bpack, rowpart, colpart);
    reduce1<<<256, 256, 0, stream>>>(rowpart, colpart, bsum, bmax);
    final_combine<<<1, 256, 0, stream>>>(bsum, bmax, out);
}